// Round 9
// baseline (3640.097 us; speedup 1.0000x reference)
//
#include <hip/hip_runtime.h>
#include <stdint.h>

#define T_STEPS 100
#define BATCH   256
#define N_IN    2048
#define N_H     1024
#define N_OUT   10
#define M_TOT   (T_STEPS * BATCH)   // 25600
#define KC      384                 // OpenBLAS SGEMM_DEFAULT_Q (Haswell/Zen)

// ---------------------------------------------------------------------------
// GEMM1 panel pass: C[m][n] (+)= sum_{k in [ks, ks+klen)} x[m][k]*W1[n][k]
// Emulates OpenBLAS sgemm K-blocking: per C element, each panel is a
// k-ascending FMA register chain from 0; panels joined by one f32 add
// (C read-modify-write between passes). first: C = s_p (beta=0).
// last: additionally add bias AFTER the final panel join (numpy's `+ b1`).
// 128x128 tile, BK=16, 256 threads, 8x8 microtile.
// ---------------------------------------------------------------------------
__global__ __launch_bounds__(256) void gemm1_panel(
    const float* __restrict__ A, const float* __restrict__ Bm,
    const float* __restrict__ bias, float* __restrict__ C,
    int ks, int klen, int first, int last) {
  __shared__ float As[16][132];   // [k][m], +4 pad
  __shared__ float Bs[16][132];   // [k][n]
  const int tid = threadIdx.x;
  const int m0 = blockIdx.x * 128;
  const int n0 = blockIdx.y * 128;
  const int tx = tid & 15;        // col group
  const int ty = tid >> 4;        // row group
  const int lrow = tid >> 2;      // 0..63
  const int lc4 = (tid & 3) * 4;  // 0,4,8,12

  float acc[8][8];
#pragma unroll
  for (int i = 0; i < 8; i++)
#pragma unroll
    for (int j = 0; j < 8; j++) acc[i][j] = 0.f;

  for (int k0 = ks; k0 < ks + klen; k0 += 16) {
#pragma unroll
    for (int i = 0; i < 2; i++) {
      const int row = lrow + i * 64;
      const float4 av = *(const float4*)(&A[(size_t)(m0 + row) * N_IN + k0 + lc4]);
      As[lc4 + 0][row] = av.x; As[lc4 + 1][row] = av.y;
      As[lc4 + 2][row] = av.z; As[lc4 + 3][row] = av.w;
      const float4 bv = *(const float4*)(&Bm[(size_t)(n0 + row) * N_IN + k0 + lc4]);
      Bs[lc4 + 0][row] = bv.x; Bs[lc4 + 1][row] = bv.y;
      Bs[lc4 + 2][row] = bv.z; Bs[lc4 + 3][row] = bv.w;
    }
    __syncthreads();
#pragma unroll
    for (int k = 0; k < 16; k++) {
      float a[8], b[8];
      *(float4*)&a[0] = *(const float4*)&As[k][ty * 8];
      *(float4*)&a[4] = *(const float4*)&As[k][ty * 8 + 4];
      *(float4*)&b[0] = *(const float4*)&Bs[k][tx * 8];
      *(float4*)&b[4] = *(const float4*)&Bs[k][tx * 8 + 4];
#pragma unroll
      for (int i = 0; i < 8; i++)
#pragma unroll
        for (int j = 0; j < 8; j++)
          acc[i][j] = __builtin_fmaf(a[i], b[j], acc[i][j]);
    }
    __syncthreads();
  }
  // join with previous panels (one f32 add), bias after last panel
#pragma unroll
  for (int i = 0; i < 8; i++) {
    const int m = m0 + ty * 8 + i;
#pragma unroll
    for (int j = 0; j < 8; j++) {
      const int n = n0 + tx * 8 + j;
      float v = acc[i][j];
      if (!first) v = __fadd_rn(C[(size_t)m * N_H + n], v);
      if (last)  v = __fadd_rn(v, bias[n]);
      C[(size_t)m * N_H + n] = v;
    }
  }
}

// ---------------------------------------------------------------------------
// Scan1: strict numpy op order (separate ufuncs, NO fma):
//   mem = ((0.9*mem) + cur) - reset
// Spikes -> packed 64-bit ballot masks.
// ---------------------------------------------------------------------------
__global__ __launch_bounds__(256) void scan1_kernel(
    const float* __restrict__ cur1, unsigned long long* __restrict__ spkbits) {
  const int b = blockIdx.x >> 2;
  const int h = (blockIdx.x & 3) * 256 + threadIdx.x;
  const int lane = threadIdx.x & 63;
  const int word = h >> 6;  // 0..15
  float mem = 0.f;
  for (int t = 0; t < T_STEPS; ++t) {
    const float c = cur1[((size_t)t * BATCH + b) * N_H + h];
    const float reset = (mem > 1.0f) ? 1.0f : 0.0f;   // previous mem
    mem = __fsub_rn(__fadd_rn(__fmul_rn(0.9f, mem), c), reset);
    const unsigned long long msk = __ballot(mem > 1.0f);
    if (lane == 0) spkbits[((size_t)t * BATCH + b) * 16 + word] = msk;
  }
}

// ---------------------------------------------------------------------------
// Layer2: one thread per (o = blockIdx.x, b = threadIdx.x).
// sgemm K=1024 with KC=384 panels: s1=[0,384), s2=[384,768), s3=[768,1024),
// each a k-ascending FMA chain; cur2 = ((s1+s2)+s3) + b2[o]; strict mem2 scan.
// f32 outputs: spk2 [100,256,10] ++ mem2 [256,10].
// ---------------------------------------------------------------------------
__global__ __launch_bounds__(256) void layer2_kernel(
    const unsigned long long* __restrict__ spkbits,
    const float* __restrict__ W2, const float* __restrict__ b2,
    float* __restrict__ out) {
  __shared__ float W2s[N_H];  // row o of W2
  const int o = blockIdx.x;
  const int b = threadIdx.x;
  for (int i = b; i < N_H; i += 256) W2s[i] = W2[(size_t)o * N_H + i];
  __syncthreads();
  const float bo = b2[o];
  float m = 0.f;
  for (int t = 0; t < T_STEPS; ++t) {
    unsigned long long w[16];
#pragma unroll
    for (int i = 0; i < 16; i++)
      w[i] = spkbits[((size_t)t * BATCH + b) * 16 + i];
    float s1 = 0.f, s2 = 0.f, s3 = 0.f;
#pragma unroll 8
    for (int h = 0; h < KC; ++h) {
      const float spk = ((w[h >> 6] >> (h & 63)) & 1ull) ? 1.0f : 0.0f;
      s1 = __builtin_fmaf(spk, W2s[h], s1);
    }
#pragma unroll 8
    for (int h = KC; h < 2 * KC; ++h) {
      const float spk = ((w[h >> 6] >> (h & 63)) & 1ull) ? 1.0f : 0.0f;
      s2 = __builtin_fmaf(spk, W2s[h], s2);
    }
#pragma unroll 8
    for (int h = 2 * KC; h < N_H; ++h) {
      const float spk = ((w[h >> 6] >> (h & 63)) & 1ull) ? 1.0f : 0.0f;
      s3 = __builtin_fmaf(spk, W2s[h], s3);
    }
    const float cur2 = __fadd_rn(__fadd_rn(__fadd_rn(s1, s2), s3), bo);
    const float reset = (m > 1.0f) ? 1.0f : 0.0f;    // previous mem2
    m = __fsub_rn(__fadd_rn(__fmul_rn(0.9f, m), cur2), reset);
    out[(size_t)t * (BATCH * N_OUT) + b * N_OUT + o] = (m > 1.0f) ? 1.0f : 0.0f;
  }
  out[(size_t)T_STEPS * BATCH * N_OUT + b * N_OUT + o] = m;
}

// ---------------------------------------------------------------------------
extern "C" void kernel_launch(void* const* d_in, const int* in_sizes, int n_in,
                              void* d_out, int out_size, void* d_ws, size_t ws_size,
                              hipStream_t stream) {
  const float* x  = (const float*)d_in[0];   // [T, B, N_IN]  f32
  const float* W1 = (const float*)d_in[1];   // [N_H, N_IN]   f32
  const float* b1 = (const float*)d_in[2];   // [N_H]         f32
  const float* W2 = (const float*)d_in[3];   // [N_OUT, N_H]  f32
  const float* b2 = (const float*)d_in[4];   // [N_OUT]       f32
  float* out = (float*)d_out;  // f32: spk2[100,256,10] ++ mem2[256,10]

  // ws: cur1 f32 (104.9MB) + spike bitmasks (3.3MB)  [proven-safe footprint]
  float* cur1 = (float*)d_ws;
  unsigned long long* bits =
      (unsigned long long*)((char*)d_ws + (size_t)M_TOT * N_H * sizeof(float));

  dim3 g1(M_TOT / 128, N_H / 128);  // 200 x 8
  for (int ks = 0, p = 0; ks < N_IN; ks += KC, ++p) {
    const int klen = (ks + KC <= N_IN) ? KC : (N_IN - ks);
    const int first = (ks == 0) ? 1 : 0;
    const int last = (ks + klen == N_IN) ? 1 : 0;
    gemm1_panel<<<g1, 256, 0, stream>>>(x, W1, b1, cur1, ks, klen, first, last);
  }
  scan1_kernel<<<BATCH * (N_H / 256), 256, 0, stream>>>(cur1, bits);
  layer2_kernel<<<N_OUT, BATCH, 0, stream>>>(bits, W2, b2, out);
}

// Round 10
// 2069.758 us; speedup vs baseline: 1.7587x; 1.7587x over previous
//
#include <hip/hip_runtime.h>
#include <stdint.h>

#define T_STEPS 100
#define BATCH   256
#define N_IN    2048
#define N_H     1024
#define N_OUT   10
#define M_TOT   (T_STEPS * BATCH)   // 25600
#define KC      384                 // OpenBLAS SGEMM_DEFAULT_Q (Haswell/Zen)

// ---------------------------------------------------------------------------
// GEMM1, all K-panels fused in one dispatch.
// Per C element: panels [0,384),[384,768),... each a k-ascending FMA register
// chain; joins are single f32 adds done IN-REGISTER (bit-identical to the
// store/reload of the multi-pass version). Bias after final join.
// 128x128 tile, BK=16, 256 threads, 8x8 microtile.
// grid.x = n-tiles (8), grid.y = m-tiles (200) so same-m blocks are adjacent
// (A-tile L2 reuse; W1 fully cache-resident).
// ---------------------------------------------------------------------------
__global__ __launch_bounds__(256) void gemm1_fused(
    const float* __restrict__ A, const float* __restrict__ Bm,
    const float* __restrict__ bias, float* __restrict__ C) {
  __shared__ float As[16][132];   // [k][m], +4 pad
  __shared__ float Bs[16][132];   // [k][n]
  const int tid = threadIdx.x;
  const int n0 = blockIdx.x * 128;
  const int m0 = blockIdx.y * 128;
  const int tx = tid & 15;        // col group
  const int ty = tid >> 4;        // row group
  const int lrow = tid >> 2;      // 0..63
  const int lc4 = (tid & 3) * 4;  // 0,4,8,12

  float run[8][8], acc[8][8];
#pragma unroll
  for (int i = 0; i < 8; i++)
#pragma unroll
    for (int j = 0; j < 8; j++) { run[i][j] = 0.f; acc[i][j] = 0.f; }
  bool folded = false;

  for (int k0 = 0; k0 < N_IN; k0 += 16) {
    // panel boundary (k0 = 384,768,1152,1536,1920): fold acc into run
    if (k0 != 0 && (k0 % KC) == 0) {
#pragma unroll
      for (int i = 0; i < 8; i++)
#pragma unroll
        for (int j = 0; j < 8; j++) {
          run[i][j] = folded ? __fadd_rn(run[i][j], acc[i][j]) : acc[i][j];
          acc[i][j] = 0.f;
        }
      folded = true;
    }
#pragma unroll
    for (int i = 0; i < 2; i++) {
      const int row = lrow + i * 64;
      const float4 av = *(const float4*)(&A[(size_t)(m0 + row) * N_IN + k0 + lc4]);
      As[lc4 + 0][row] = av.x; As[lc4 + 1][row] = av.y;
      As[lc4 + 2][row] = av.z; As[lc4 + 3][row] = av.w;
      const float4 bv = *(const float4*)(&Bm[(size_t)(n0 + row) * N_IN + k0 + lc4]);
      Bs[lc4 + 0][row] = bv.x; Bs[lc4 + 1][row] = bv.y;
      Bs[lc4 + 2][row] = bv.z; Bs[lc4 + 3][row] = bv.w;
    }
    __syncthreads();
#pragma unroll
    for (int k = 0; k < 16; k++) {
      float a[8], b[8];
      *(float4*)&a[0] = *(const float4*)&As[k][ty * 8];
      *(float4*)&a[4] = *(const float4*)&As[k][ty * 8 + 4];
      *(float4*)&b[0] = *(const float4*)&Bs[k][tx * 8];
      *(float4*)&b[4] = *(const float4*)&Bs[k][tx * 8 + 4];
#pragma unroll
      for (int i = 0; i < 8; i++)
#pragma unroll
        for (int j = 0; j < 8; j++)
          acc[i][j] = __builtin_fmaf(a[i], b[j], acc[i][j]);
    }
    __syncthreads();
  }
  // final panel join + bias, store
#pragma unroll
  for (int i = 0; i < 8; i++) {
    const int m = m0 + ty * 8 + i;
#pragma unroll
    for (int j = 0; j < 8; j += 4) {
      const int n = n0 + tx * 8 + j;
      float4 v;
      v.x = __fadd_rn(__fadd_rn(run[i][j + 0], acc[i][j + 0]), bias[n + 0]);
      v.y = __fadd_rn(__fadd_rn(run[i][j + 1], acc[i][j + 1]), bias[n + 1]);
      v.z = __fadd_rn(__fadd_rn(run[i][j + 2], acc[i][j + 2]), bias[n + 2]);
      v.w = __fadd_rn(__fadd_rn(run[i][j + 3], acc[i][j + 3]), bias[n + 3]);
      *(float4*)&C[(size_t)m * N_H + n] = v;
    }
  }
}

// ---------------------------------------------------------------------------
// Scan1: strict numpy op order (no fma): mem = ((0.9*mem) + cur) - reset.
// Spikes -> packed 64-bit ballot masks.
// ---------------------------------------------------------------------------
__global__ __launch_bounds__(256) void scan1_kernel(
    const float* __restrict__ cur1, unsigned long long* __restrict__ spkbits) {
  const int b = blockIdx.x >> 2;
  const int h = (blockIdx.x & 3) * 256 + threadIdx.x;
  const int lane = threadIdx.x & 63;
  const int word = h >> 6;  // 0..15
  float mem = 0.f;
  for (int t = 0; t < T_STEPS; ++t) {
    const float c = cur1[((size_t)t * BATCH + b) * N_H + h];
    const float reset = (mem > 1.0f) ? 1.0f : 0.0f;   // previous mem
    mem = __fsub_rn(__fadd_rn(__fmul_rn(0.9f, mem), c), reset);
    const unsigned long long msk = __ballot(mem > 1.0f);
    if (lane == 0) spkbits[((size_t)t * BATCH + b) * 16 + word] = msk;
  }
}

// ---------------------------------------------------------------------------
// cur2 (parallel over t,b,o): same 3-panel k-ascending FMA chains as before —
// s1=[0,384), s2=[384,768), s3=[768,1024); cur2 = ((s1+s2)+s3) + b2[o].
// One thread per (t,b,o) = 256000 threads -> fully occupied, latency hidden.
// ---------------------------------------------------------------------------
__global__ __launch_bounds__(256) void cur2_kernel(
    const unsigned long long* __restrict__ spkbits,
    const float* __restrict__ W2, const float* __restrict__ b2,
    float* __restrict__ cur2) {
  const int g = blockIdx.x * 256 + threadIdx.x;   // ((t*256)+b)*10 + o
  const int tb = g / N_OUT;                       // t*256 + b
  const int o = g - tb * N_OUT;
  unsigned long long w[16];
#pragma unroll
  for (int i = 0; i < 16; i++) w[i] = spkbits[(size_t)tb * 16 + i];
  const float* W2o = &W2[(size_t)o * N_H];
  float s1 = 0.f, s2 = 0.f, s3 = 0.f;
#pragma unroll 8
  for (int h = 0; h < KC; ++h) {
    const float spk = ((w[h >> 6] >> (h & 63)) & 1ull) ? 1.0f : 0.0f;
    s1 = __builtin_fmaf(spk, W2o[h], s1);
  }
#pragma unroll 8
  for (int h = KC; h < 2 * KC; ++h) {
    const float spk = ((w[h >> 6] >> (h & 63)) & 1ull) ? 1.0f : 0.0f;
    s2 = __builtin_fmaf(spk, W2o[h], s2);
  }
#pragma unroll 8
  for (int h = 2 * KC; h < N_H; ++h) {
    const float spk = ((w[h >> 6] >> (h & 63)) & 1ull) ? 1.0f : 0.0f;
    s3 = __builtin_fmaf(spk, W2o[h], s3);
  }
  cur2[g] = __fadd_rn(__fadd_rn(__fadd_rn(s1, s2), s3), b2[o]);
}

// ---------------------------------------------------------------------------
// Scan2: strict mem2 scan over t per (b,o); writes spk2 + final mem2 (f32).
// 2560 threads, coalesced cur2/out access.
// ---------------------------------------------------------------------------
__global__ __launch_bounds__(256) void scan2_kernel(
    const float* __restrict__ cur2, float* __restrict__ out) {
  const int g = blockIdx.x * 256 + threadIdx.x;   // b*10 + o
  float m = 0.f;
  for (int t = 0; t < T_STEPS; ++t) {
    const float c = cur2[(size_t)t * (BATCH * N_OUT) + g];
    const float reset = (m > 1.0f) ? 1.0f : 0.0f;   // previous mem2
    m = __fsub_rn(__fadd_rn(__fmul_rn(0.9f, m), c), reset);
    out[(size_t)t * (BATCH * N_OUT) + g] = (m > 1.0f) ? 1.0f : 0.0f;
  }
  out[(size_t)T_STEPS * (BATCH * N_OUT) + g] = m;
}

// ---------------------------------------------------------------------------
extern "C" void kernel_launch(void* const* d_in, const int* in_sizes, int n_in,
                              void* d_out, int out_size, void* d_ws, size_t ws_size,
                              hipStream_t stream) {
  const float* x  = (const float*)d_in[0];   // [T, B, N_IN]  f32
  const float* W1 = (const float*)d_in[1];   // [N_H, N_IN]   f32
  const float* b1 = (const float*)d_in[2];   // [N_H]         f32
  const float* W2 = (const float*)d_in[3];   // [N_OUT, N_H]  f32
  const float* b2 = (const float*)d_in[4];   // [N_OUT]       f32
  float* out = (float*)d_out;  // f32: spk2[100,256,10] ++ mem2[256,10]

  // ws: cur1 f32 (104.9MB) | bits (3.3MB) | cur2 f32 (1.02MB)
  char* p = (char*)d_ws;
  float* cur1 = (float*)p;                           p += (size_t)M_TOT * N_H * 4;
  unsigned long long* bits = (unsigned long long*)p; p += (size_t)M_TOT * 16 * 8;
  float* cur2 = (float*)p;

  dim3 g1(N_H / 128, M_TOT / 128);  // (8, 200)
  gemm1_fused<<<g1, 256, 0, stream>>>(x, W1, b1, cur1);
  scan1_kernel<<<BATCH * (N_H / 256), 256, 0, stream>>>(cur1, bits);
  cur2_kernel<<<(M_TOT * N_OUT) / 256, 256, 0, stream>>>(bits, W2, b2, cur2);
  scan2_kernel<<<(BATCH * N_OUT) / 256, 256, 0, stream>>>(cur2, out);
}

// Round 11
// 2028.226 us; speedup vs baseline: 1.7947x; 1.0205x over previous
//
#include <hip/hip_runtime.h>
#include <stdint.h>

#define T_STEPS 100
#define BATCH   256
#define N_IN    2048
#define N_H     1024
#define N_OUT   10
#define M_TOT   (T_STEPS * BATCH)   // 25600
#define KC      384                 // OpenBLAS SGEMM_DEFAULT_Q (Haswell/Zen)

// ---------------------------------------------------------------------------
// GEMM1, all K-panels fused, conflict-free LDS reads, XCD-aware block map.
// Per C element: panels [0,384),[384,768),... each a k-ascending FMA register
// chain; joins are single f32 adds in-register; bias after final join.
// 128x128 tile, BK=16, 256 threads, 8x8 microtile.
// Thread (tx,ty) owns rows ty*8..+7 and cols {tx*4..+3, 64+tx*4..+3}:
//   B-read chunk-groups = tx%8 -> 2-way bank aliasing only (free).
// Block map: 1-D grid, xcd = id&7 owns m-strip [xcd*25, xcd*25+25); the 8
// n-tiles of one m-tile are consecutive on that XCD -> A-tile L2-resident.
// ---------------------------------------------------------------------------
__global__ __launch_bounds__(256) void gemm1_fused(
    const float* __restrict__ A, const float* __restrict__ Bm,
    const float* __restrict__ bias, float* __restrict__ C) {
  __shared__ float As[16][132];   // [k][m], +4 pad
  __shared__ float Bs[16][132];   // [k][n]
  const int tid = threadIdx.x;
  const int id = blockIdx.x;
  const int xcd = id & 7;
  const int j = id >> 3;               // 0..199 sequential per XCD
  const int m0 = (xcd * 25 + (j >> 3)) * 128;
  const int n0 = (j & 7) * 128;
  const int tx = tid & 15;        // col group
  const int ty = tid >> 4;        // row group
  const int lrow = tid >> 2;      // 0..63
  const int lc4 = (tid & 3) * 4;  // 0,4,8,12

  float run[8][8], acc[8][8];
#pragma unroll
  for (int i = 0; i < 8; i++)
#pragma unroll
    for (int j2 = 0; j2 < 8; j2++) { run[i][j2] = 0.f; acc[i][j2] = 0.f; }
  bool folded = false;

  for (int k0 = 0; k0 < N_IN; k0 += 16) {
    // panel boundary (k0 = 384,768,1152,1536,1920): fold acc into run
    if (k0 != 0 && (k0 % KC) == 0) {
#pragma unroll
      for (int i = 0; i < 8; i++)
#pragma unroll
        for (int j2 = 0; j2 < 8; j2++) {
          run[i][j2] = folded ? __fadd_rn(run[i][j2], acc[i][j2]) : acc[i][j2];
          acc[i][j2] = 0.f;
        }
      folded = true;
    }
#pragma unroll
    for (int i = 0; i < 2; i++) {
      const int row = lrow + i * 64;
      const float4 av = *(const float4*)(&A[(size_t)(m0 + row) * N_IN + k0 + lc4]);
      As[lc4 + 0][row] = av.x; As[lc4 + 1][row] = av.y;
      As[lc4 + 2][row] = av.z; As[lc4 + 3][row] = av.w;
      const float4 bv = *(const float4*)(&Bm[(size_t)(n0 + row) * N_IN + k0 + lc4]);
      Bs[lc4 + 0][row] = bv.x; Bs[lc4 + 1][row] = bv.y;
      Bs[lc4 + 2][row] = bv.z; Bs[lc4 + 3][row] = bv.w;
    }
    __syncthreads();
#pragma unroll
    for (int k = 0; k < 16; k++) {
      float a[8], b[8];
      *(float4*)&a[0] = *(const float4*)&As[k][ty * 8];
      *(float4*)&a[4] = *(const float4*)&As[k][ty * 8 + 4];
      *(float4*)&b[0] = *(const float4*)&Bs[k][tx * 4];        // cols tx*4..+3
      *(float4*)&b[4] = *(const float4*)&Bs[k][64 + tx * 4];   // cols 64+tx*4..+3
#pragma unroll
      for (int i = 0; i < 8; i++)
#pragma unroll
        for (int j2 = 0; j2 < 8; j2++)
          acc[i][j2] = __builtin_fmaf(a[i], b[j2], acc[i][j2]);
    }
    __syncthreads();
  }
  // final panel join + bias, store (two float4 column groups)
#pragma unroll
  for (int i = 0; i < 8; i++) {
    const int m = m0 + ty * 8 + i;
    const int n1 = n0 + tx * 4;
    const int n2 = n0 + 64 + tx * 4;
    float4 v1, v2;
    v1.x = __fadd_rn(__fadd_rn(run[i][0], acc[i][0]), bias[n1 + 0]);
    v1.y = __fadd_rn(__fadd_rn(run[i][1], acc[i][1]), bias[n1 + 1]);
    v1.z = __fadd_rn(__fadd_rn(run[i][2], acc[i][2]), bias[n1 + 2]);
    v1.w = __fadd_rn(__fadd_rn(run[i][3], acc[i][3]), bias[n1 + 3]);
    v2.x = __fadd_rn(__fadd_rn(run[i][4], acc[i][4]), bias[n2 + 0]);
    v2.y = __fadd_rn(__fadd_rn(run[i][5], acc[i][5]), bias[n2 + 1]);
    v2.z = __fadd_rn(__fadd_rn(run[i][6], acc[i][6]), bias[n2 + 2]);
    v2.w = __fadd_rn(__fadd_rn(run[i][7], acc[i][7]), bias[n2 + 3]);
    *(float4*)&C[(size_t)m * N_H + n1] = v1;
    *(float4*)&C[(size_t)m * N_H + n2] = v2;
  }
}

// ---------------------------------------------------------------------------
// Scan1: strict numpy op order (no fma): mem = ((0.9*mem) + cur) - reset.
// Spikes -> packed 64-bit ballot masks.
// ---------------------------------------------------------------------------
__global__ __launch_bounds__(256) void scan1_kernel(
    const float* __restrict__ cur1, unsigned long long* __restrict__ spkbits) {
  const int b = blockIdx.x >> 2;
  const int h = (blockIdx.x & 3) * 256 + threadIdx.x;
  const int lane = threadIdx.x & 63;
  const int word = h >> 6;  // 0..15
  float mem = 0.f;
  for (int t = 0; t < T_STEPS; ++t) {
    const float c = cur1[((size_t)t * BATCH + b) * N_H + h];
    const float reset = (mem > 1.0f) ? 1.0f : 0.0f;   // previous mem
    mem = __fsub_rn(__fadd_rn(__fmul_rn(0.9f, mem), c), reset);
    const unsigned long long msk = __ballot(mem > 1.0f);
    if (lane == 0) spkbits[((size_t)t * BATCH + b) * 16 + word] = msk;
  }
}

// ---------------------------------------------------------------------------
// cur2 (parallel over t,b,o): 3-panel k-ascending FMA chains —
// s1=[0,384), s2=[384,768), s3=[768,1024); cur2 = ((s1+s2)+s3) + b2[o].
// ---------------------------------------------------------------------------
__global__ __launch_bounds__(256) void cur2_kernel(
    const unsigned long long* __restrict__ spkbits,
    const float* __restrict__ W2, const float* __restrict__ b2,
    float* __restrict__ cur2) {
  const int g = blockIdx.x * 256 + threadIdx.x;   // ((t*256)+b)*10 + o
  const int tb = g / N_OUT;                       // t*256 + b
  const int o = g - tb * N_OUT;
  unsigned long long w[16];
#pragma unroll
  for (int i = 0; i < 16; i++) w[i] = spkbits[(size_t)tb * 16 + i];
  const float* W2o = &W2[(size_t)o * N_H];
  float s1 = 0.f, s2 = 0.f, s3 = 0.f;
#pragma unroll 8
  for (int h = 0; h < KC; ++h) {
    const float spk = ((w[h >> 6] >> (h & 63)) & 1ull) ? 1.0f : 0.0f;
    s1 = __builtin_fmaf(spk, W2o[h], s1);
  }
#pragma unroll 8
  for (int h = KC; h < 2 * KC; ++h) {
    const float spk = ((w[h >> 6] >> (h & 63)) & 1ull) ? 1.0f : 0.0f;
    s2 = __builtin_fmaf(spk, W2o[h], s2);
  }
#pragma unroll 8
  for (int h = 2 * KC; h < N_H; ++h) {
    const float spk = ((w[h >> 6] >> (h & 63)) & 1ull) ? 1.0f : 0.0f;
    s3 = __builtin_fmaf(spk, W2o[h], s3);
  }
  cur2[g] = __fadd_rn(__fadd_rn(__fadd_rn(s1, s2), s3), b2[o]);
}

// ---------------------------------------------------------------------------
// Scan2: strict mem2 scan over t per (b,o); writes spk2 + final mem2 (f32).
// ---------------------------------------------------------------------------
__global__ __launch_bounds__(256) void scan2_kernel(
    const float* __restrict__ cur2, float* __restrict__ out) {
  const int g = blockIdx.x * 256 + threadIdx.x;   // b*10 + o
  float m = 0.f;
  for (int t = 0; t < T_STEPS; ++t) {
    const float c = cur2[(size_t)t * (BATCH * N_OUT) + g];
    const float reset = (m > 1.0f) ? 1.0f : 0.0f;   // previous mem2
    m = __fsub_rn(__fadd_rn(__fmul_rn(0.9f, m), c), reset);
    out[(size_t)t * (BATCH * N_OUT) + g] = (m > 1.0f) ? 1.0f : 0.0f;
  }
  out[(size_t)T_STEPS * (BATCH * N_OUT) + g] = m;
}

// ---------------------------------------------------------------------------
extern "C" void kernel_launch(void* const* d_in, const int* in_sizes, int n_in,
                              void* d_out, int out_size, void* d_ws, size_t ws_size,
                              hipStream_t stream) {
  const float* x  = (const float*)d_in[0];   // [T, B, N_IN]  f32
  const float* W1 = (const float*)d_in[1];   // [N_H, N_IN]   f32
  const float* b1 = (const float*)d_in[2];   // [N_H]         f32
  const float* W2 = (const float*)d_in[3];   // [N_OUT, N_H]  f32
  const float* b2 = (const float*)d_in[4];   // [N_OUT]       f32
  float* out = (float*)d_out;  // f32: spk2[100,256,10] ++ mem2[256,10]

  // ws: cur1 f32 (104.9MB) | bits (3.3MB) | cur2 f32 (1.02MB)
  char* p = (char*)d_ws;
  float* cur1 = (float*)p;                           p += (size_t)M_TOT * N_H * 4;
  unsigned long long* bits = (unsigned long long*)p; p += (size_t)M_TOT * 16 * 8;
  float* cur2 = (float*)p;

  gemm1_fused<<<(M_TOT / 128) * (N_H / 128), 256, 0, stream>>>(x, W1, b1, cur1);
  scan1_kernel<<<BATCH * (N_H / 256), 256, 0, stream>>>(cur1, bits);
  cur2_kernel<<<(M_TOT * N_OUT) / 256, 256, 0, stream>>>(bits, W2, b2, cur2);
  scan2_kernel<<<(BATCH * N_OUT) / 256, 256, 0, stream>>>(cur2, out);
}